// Round 4
// baseline (313.233 us; speedup 1.0000x reference)
//
#include <hip/hip_runtime.h>
#include <math.h>

// Round 12: 8-phase-style 256x256 GEMM in 64KB LDS (no hipFuncSetAttribute,
// no >64KB launch — suspected cause of R11's container failure).
// BK=32, 8 waves (2Mx4N), dbuf x (A 16KB | B0 8KB | B1 8KB) = 65536 B.
// Per tile 2 phases: p0 {read A+B0, stage B1(t+1), MFMA j0-1},
//                    p1 {read B1, stage A/B0(t+2), MFMA j2-3}.
// Counted vmcnt: WAITV(4)/WAITV(4) steady (4-7 loads in flight, never 0),
// tails WAITV(1)/WAITV(0). setprio(1) around MFMA clusters.
//   D1 prep_all : X->f16 || Wq,Wk bf16-split || Wv transpose->f16
//   D2 mt       : Mt = Wk_s Wq_s^T (split-bf16 3-MFMA, 128^2) -> f16
//   D3 tv8      : T = Xf.Mt^T (bx<4) || Vt = (Xf.Wvt)^T (bx>=4)
//   D4 sc8      : Sc = T . Xf^T -> fp32
//   D5 softmax  : P = softmax(Sc) -> f16
//   D6 pv8      : out = P . Vt^T

typedef __bf16 bf16;
typedef _Float16 f16;
typedef __bf16 bf16x8 __attribute__((ext_vector_type(8)));
typedef __bf16 bf16x4 __attribute__((ext_vector_type(4)));
typedef _Float16 f16x4 __attribute__((ext_vector_type(4)));
typedef _Float16 f16x8 __attribute__((ext_vector_type(8)));
typedef float  f32x4  __attribute__((ext_vector_type(4)));

template<typename E> struct vec8_of;
template<> struct vec8_of<bf16> { using type = bf16x8; };
template<> struct vec8_of<f16>  { using type = f16x8; };

__device__ inline f32x4 mfma16(bf16x8 a, bf16x8 b, f32x4 c) {
    return __builtin_amdgcn_mfma_f32_16x16x32_bf16(a, b, c, 0, 0, 0);
}
__device__ inline f32x4 mfma16(f16x8 a, f16x8 b, f32x4 c) {
    return __builtin_amdgcn_mfma_f32_16x16x32_f16(a, b, c, 0, 0, 0);
}

#define AS1 __attribute__((address_space(1)))
#define AS3 __attribute__((address_space(3)))

template<typename E>
__device__ inline void async_load16(const E* g, void* l) {
    __builtin_amdgcn_global_load_lds((const AS1 unsigned int*)g,
                                     (AS3 unsigned int*)l, 16, 0, 0);
}

#define SBAR()  do { __builtin_amdgcn_s_barrier(); __builtin_amdgcn_sched_barrier(0); } while (0)
#define WAITV(n) do { asm volatile("s_waitcnt vmcnt(" #n ")" ::: "memory"); __builtin_amdgcn_sched_barrier(0); } while (0)
#define WAITL() do { asm volatile("s_waitcnt lgkmcnt(0)" ::: "memory"); __builtin_amdgcn_sched_barrier(0); } while (0)

// ============== 8-phase 256x256 f16 GEMM body, 64KB LDS ==============
// C[M,N] = sum_k A[m,k]*B[n,k]   (B in [N,K] layout).
// OUT_MODE: 0 fp32; 1 f16; 2 f16 transposed per-batch (Vt path).
template<int OUT_MODE>
__device__ __forceinline__ void gemm8_body(
    char* __restrict__ smraw,
    const f16* __restrict__ A, const f16* __restrict__ B,
    float* __restrict__ Cf, f16* __restrict__ Ch,
    int K, int lda, int ldb, int ldc,
    long long sA, long long sB, long long sC,
    int bx, int by, int bz)
{
    A += (long long)bz * sA;
    B += (long long)bz * sB;

    const int tid  = threadIdx.x;
    const int lane = tid & 63;
    const int wave = tid >> 6;      // 0..7
    const int quad = lane >> 4;
    const int l16  = lane & 15;
    const int wm   = wave >> 2;     // 0..1  (M half, 128 rows)
    const int wn   = wave & 3;      // 0..3  (N quarter, 64 cols)

    const long long rowA0 = (long long)by * 256;
    const long long colB0 = (long long)bx * 256;

    // ---- staging precompute (source pre-swizzled; LDS dest linear) ----
    // A chunk [256 rows][32k] f16 = 16KB: slots s = tid, 512+tid.
    // B half-chunk [128 rows][32k] = 8KB: slot s = tid.
    // swizzle key for slot s: (s>>4)&3 ; col8 = ((s&3)^key)*8.
    const int s0 = tid, s1 = 512 + tid;
    const int aRow0 = s0 >> 2, aRow1 = s1 >> 2;
    const int aCol0 = ((s0 & 3) ^ ((s0 >> 4) & 3)) * 8;
    const int aCol1 = ((s1 & 3) ^ ((s1 >> 4) & 3)) * 8;
    const int ci    = s0 >> 2;                       // 0..127
    const int bRow0 = (ci >> 5) * 64 + (ci & 31);    // bit5 = 0 rows
    const int bCol  = aCol0;                         // same slot math

    const f16* aSrc0 = A + (rowA0 + aRow0) * lda + aCol0;
    const f16* aSrc1 = A + (rowA0 + aRow1) * lda + aCol1;
    const f16* b0Src = B + (colB0 + bRow0) * ldb + bCol;
    const f16* b1Src = b0Src + 32LL * ldb;           // bit5 = 1 rows

    const int dA0 = tid * 16, dA1 = 8192 + tid * 16, dB = tid * 16;

    const int nt = K >> 5;

    auto stageA = [&](int t) {
        char* buf = smraw + ((t & 1) << 15);
        async_load16(aSrc0 + t * 32, buf + dA0);
        async_load16(aSrc1 + t * 32, buf + dA1);
    };
    auto stageB0 = [&](int t) {
        char* buf = smraw + ((t & 1) << 15);
        async_load16(b0Src + t * 32, buf + 16384 + dB);
    };
    auto stageB1 = [&](int t) {
        char* buf = smraw + ((t & 1) << 15);
        async_load16(b1Src + t * 32, buf + 24576 + dB);
    };

    // ---- LDS read offsets (swizzle matches staging involution) ----
    const int lofs = l16 * 64 + ((quad ^ ((l16 >> 2) & 3)) << 4);
    const int aoff = wm * 8192 + lofs;               // + i*1024
    const int boff = wn * 2048 + lofs;               // + j*1024 (within half)

    f32x4 acc[8][4];
#pragma unroll
    for (int i = 0; i < 8; i++)
#pragma unroll
        for (int j = 0; j < 4; j++) acc[i][j] = (f32x4){0.f, 0.f, 0.f, 0.f};

    // ---- prologue: 7 loads; WAITV(4) lands A(0),B0(0) ----
    stageA(0); stageB0(0); stageB1(0);
    stageA(1); stageB0(1);
    WAITV(4);
    SBAR();

    for (int t = 0; t < nt; t++) {
        const char* buf = smraw + ((t & 1) << 15);
        f16x8 av[8], bv[2];

        // ======== p0: A + B0 reads, MFMA j0-1, stage B1(t+1) ========
#pragma unroll
        for (int i = 0; i < 8; i++) av[i] = *(const f16x8*)(buf + aoff + i * 1024);
#pragma unroll
        for (int j = 0; j < 2; j++) bv[j] = *(const f16x8*)(buf + 16384 + boff + j * 1024);
        if (t + 1 < nt) stageB1(t + 1);
        SBAR();
        WAITL();
        __builtin_amdgcn_s_setprio(1);
#pragma unroll
        for (int i = 0; i < 8; i++) {
            acc[i][0] = mfma16(av[i], bv[0], acc[i][0]);
            acc[i][1] = mfma16(av[i], bv[1], acc[i][1]);
        }
        __builtin_amdgcn_s_setprio(0);
        if (t + 1 < nt) { WAITV(4); } else { WAITV(0); }   // B1(t) landed
        SBAR();

        // ======== p1: B1 reads, MFMA j2-3, stage A/B0(t+2) ========
#pragma unroll
        for (int j = 0; j < 2; j++) bv[j] = *(const f16x8*)(buf + 24576 + boff + j * 1024);
        if (t + 2 < nt) { stageA(t + 2); stageB0(t + 2); }
        SBAR();
        WAITL();
        __builtin_amdgcn_s_setprio(1);
#pragma unroll
        for (int i = 0; i < 8; i++) {
            acc[i][2] = mfma16(av[i], bv[0], acc[i][2]);
            acc[i][3] = mfma16(av[i], bv[1], acc[i][3]);
        }
        __builtin_amdgcn_s_setprio(0);
        if (t + 2 < nt) { WAITV(4); }                      // A,B0(t+1) landed
        else if (t + 1 < nt) { WAITV(1); }
        SBAR();
    }

    // ================= epilogue =================
    if (OUT_MODE == 2) {
        // Vt transpose via LDS [256 cols][72] f16 (36KB), 4 passes (h, iq).
        auto tr = (f16(*)[72])smraw;
        const int batch = (int)(rowA0 >> 11);
        const long long rib = rowA0 & 2047;
        const int c  = tid >> 1;          // 0..255: Vt row (= C col)
        const int r0 = (tid & 1) << 5;    // 0 / 32
#pragma unroll
        for (int h = 0; h < 2; h++)
#pragma unroll
            for (int iq = 0; iq < 2; iq++) {
                __syncthreads();
                if (wm == h) {
#pragma unroll
                    for (int i2 = 0; i2 < 4; i2++)
#pragma unroll
                        for (int j = 0; j < 4; j++)
#pragma unroll
                            for (int e = 0; e < 4; e++)
                                tr[wn * 64 + j * 16 + l16][i2 * 16 + quad * 4 + e] =
                                    (f16)acc[iq * 4 + i2][j][e];
                }
                __syncthreads();
                f16* vt = Ch + (long long)batch * 1024 * 2048 +
                          (long long)(colB0 + c) * ldc + rib + h * 128 + iq * 64 + r0;
#pragma unroll
                for (int u = 0; u < 32; u += 8)
                    *(f16x8*)(vt + u) = *(const f16x8*)&tr[c][r0 + u];
            }
        return;
    }

    const long long cOff = (long long)bz * sC +
                           (rowA0 + wm * 128 + quad * 4) * (long long)ldc +
                           colB0 + wn * 64 + l16;
#pragma unroll
    for (int i = 0; i < 8; i++)
#pragma unroll
        for (int e = 0; e < 4; e++) {
            const long long ro = cOff + (long long)(i * 16 + e) * ldc;
            if (OUT_MODE == 0) {
                float* rp = Cf + ro;
#pragma unroll
                for (int j = 0; j < 4; j++) rp[j * 16] = acc[i][j][e];
            } else {
                f16* rp = Ch + ro;
#pragma unroll
                for (int j = 0; j < 4; j++) rp[j * 16] = (f16)acc[i][j][e];
            }
        }
}

// ---- D3: T = Xf.Mt^T (bx<4) || Vt = (Xf.Wvt)^T (bx>=4) ----
__global__ __launch_bounds__(512, 2) void tv8(
    const f16* __restrict__ Xf, const f16* __restrict__ Mt_f,
    const f16* __restrict__ Wvt_f, f16* __restrict__ T, f16* __restrict__ Vt)
{
    extern __shared__ char smraw[];
    if (blockIdx.x < 4)
        gemm8_body<1>(smraw, Xf, Mt_f, nullptr, T, 1024, 1024, 1024, 1024,
                      0, 0, 0, blockIdx.x, blockIdx.y, 0);
    else
        gemm8_body<2>(smraw, Xf, Wvt_f, nullptr, Vt, 1024, 1024, 1024, 2048,
                      0, 0, 0, blockIdx.x - 4, blockIdx.y, 0);
}

// ---- generic 8-phase wrapper (D4 Sc, D6 PV) ----
template<int OUT_MODE>
__global__ __launch_bounds__(512, 2) void gemm8_k(
    const f16* __restrict__ A, const f16* __restrict__ B,
    float* __restrict__ Cf, f16* __restrict__ Ch,
    int K, int lda, int ldb, int ldc,
    long long sA, long long sB, long long sC)
{
    extern __shared__ char smraw[];
    gemm8_body<OUT_MODE>(smraw, A, B, Cf, Ch, K, lda, ldb, ldc, sA, sB, sC,
                         blockIdx.x, blockIdx.y, blockIdx.z);
}

// ============== 128^2 kernel (Mt only: split-bf16 3-MFMA) — verified R10 ====
template<typename E, bool SPLIT, int OUT_MODE, int BK>
__device__ __forceinline__ void gemm_body(
    char* __restrict__ smraw,
    const E* __restrict__ Ahi, const E* __restrict__ Alo,
    const E* __restrict__ Bhi, const E* __restrict__ Blo,
    float* __restrict__ Cf, f16* __restrict__ Ch,
    int K, int lda, int ldb, int ldc,
    long long sA, long long sB, long long sC,
    int bx, int by, int bz)
{
    using vec8 = typename vec8_of<E>::type;
    constexpr int TILE_BYTES = 128 * BK * (int)sizeof(E);
    constexpr int CPW = (TILE_BYTES / 1024) / 4;
    constexpr int SPR = (BK * (int)sizeof(E)) / 16;

    Ahi += (long long)bz * sA;
    Bhi += (long long)bz * sB;
    if (SPLIT) { Alo += (long long)bz * sA; Blo += (long long)bz * sB; }

    const int tid  = threadIdx.x;
    const int lane = tid & 63;
    const int wave = tid >> 6;
    const int quad = lane >> 4;
    const int l16  = lane & 15;
    const int wm   = (wave >> 1) * 64;
    const int wn   = (wave & 1) * 64;

    const long long rowA0 = (long long)by * 128;
    const long long colB0 = (long long)bx * 128;

    auto swz = [](int r) -> int { return (SPR == 8) ? (r & 7) : ((r >> 1) & 3); };

    int ofs[CPW], rr[CPW], cc8[CPW];
#pragma unroll
    for (int u = 0; u < CPW; u++) {
        ofs[u] = (wave * CPW + u) * 1024 + lane * 16;
        const int s = ofs[u] >> 4;
        rr[u]  = s / SPR;
        cc8[u] = (s & (SPR - 1)) ^ swz(rr[u]);
    }

    f32x4 acc[4][4];
#pragma unroll
    for (int i = 0; i < 4; i++)
#pragma unroll
        for (int j = 0; j < 4; j++) acc[i][j] = (f32x4){0.f, 0.f, 0.f, 0.f};

    for (int k0 = 0; k0 < K; k0 += BK) {
#pragma unroll
        for (int u = 0; u < CPW; u++) {
            async_load16(Ahi + (rowA0 + rr[u]) * lda + k0 + cc8[u] * 8, smraw + 0 * TILE_BYTES + ofs[u]);
            async_load16(Bhi + (colB0 + rr[u]) * ldb + k0 + cc8[u] * 8, smraw + 1 * TILE_BYTES + ofs[u]);
            if (SPLIT) {
                async_load16(Alo + (rowA0 + rr[u]) * lda + k0 + cc8[u] * 8, smraw + 2 * TILE_BYTES + ofs[u]);
                async_load16(Blo + (colB0 + rr[u]) * ldb + k0 + cc8[u] * 8, smraw + 3 * TILE_BYTES + ofs[u]);
            }
        }
        __syncthreads();

#pragma unroll
        for (int kh = 0; kh < BK / 32; kh++) {
            const int kc8 = kh * 4 + quad;
            vec8 a_hi[4], b_hi[4], a_lo[4], b_lo[4];
#pragma unroll
            for (int i = 0; i < 4; i++) {
                const int ra = wm + i * 16 + l16;
                const int rb = wn + i * 16 + l16;
                const int oa = ra * (SPR * 16) + ((kc8 ^ swz(ra)) << 4);
                const int ob = rb * (SPR * 16) + ((kc8 ^ swz(rb)) << 4);
                a_hi[i] = *(const vec8*)(smraw + 0 * TILE_BYTES + oa);
                b_hi[i] = *(const vec8*)(smraw + 1 * TILE_BYTES + ob);
                if (SPLIT) {
                    a_lo[i] = *(const vec8*)(smraw + 2 * TILE_BYTES + oa);
                    b_lo[i] = *(const vec8*)(smraw + 3 * TILE_BYTES + ob);
                }
            }
#pragma unroll
            for (int i = 0; i < 4; i++)
#pragma unroll
                for (int j = 0; j < 4; j++) {
                    acc[i][j] = mfma16(a_hi[i], b_hi[j], acc[i][j]);
                    if (SPLIT) {
                        acc[i][j] = mfma16(a_hi[i], b_lo[j], acc[i][j]);
                        acc[i][j] = mfma16(a_lo[i], b_hi[j], acc[i][j]);
                    }
                }
        }
        __syncthreads();
    }

    const long long cOff = (long long)bz * sC +
                           (rowA0 + wm + quad * 4) * (long long)ldc + colB0 + wn + l16;
#pragma unroll
    for (int i = 0; i < 4; i++)
#pragma unroll
        for (int e = 0; e < 4; e++) {
            const long long ro = cOff + (i * 16 + e) * ldc;
            if (OUT_MODE == 0) {
                float* rp = Cf + ro;
#pragma unroll
                for (int j = 0; j < 4; j++) rp[j * 16] = acc[i][j][e];
            } else {
                f16* rp = Ch + ro;
#pragma unroll
                for (int j = 0; j < 4; j++) rp[j * 16] = (f16)acc[i][j][e];
            }
        }
}

template<typename E, bool SPLIT, int OUT_MODE, int BK>
__global__ __launch_bounds__(256) void gemm_bt(
    const E* __restrict__ Ahi, const E* __restrict__ Alo,
    const E* __restrict__ Bhi, const E* __restrict__ Blo,
    float* __restrict__ Cf, f16* __restrict__ Ch,
    int K, int lda, int ldb, int ldc,
    long long sA, long long sB, long long sC)
{
    extern __shared__ char smraw[];
    gemm_body<E, SPLIT, OUT_MODE, BK>(smraw, Ahi, Alo, Bhi, Blo, Cf, Ch,
                                      K, lda, ldb, ldc, sA, sB, sC,
                                      blockIdx.x, blockIdx.y, blockIdx.z);
}

// ---- D1: X->f16 || Wq,Wk bf16-split || Wv transpose->f16 ----
__global__ __launch_bounds__(256) void prep_all(
    const float4* __restrict__ X, f16* __restrict__ Xf,
    const float* __restrict__ Wq, const float* __restrict__ Wk, const float* __restrict__ Wv,
    bf16* __restrict__ Wq_h, bf16* __restrict__ Wq_l,
    bf16* __restrict__ Wk_h, bf16* __restrict__ Wk_l,
    f16* __restrict__ Wvt_f)
{
    int b = blockIdx.x;
    if (b < 8192) {
        long long i = (long long)b * 256 + threadIdx.x;
        float4 v = X[i];
        f16x4 fv = {(f16)v.x, (f16)v.y, (f16)v.z, (f16)v.w};
        *(f16x4*)(Xf + 4 * i) = fv;
    } else if (b < 10240) {
        const int b2 = b - 8192;
        const float4* W = (const float4*)(b2 < 1024 ? Wq : Wk);
        bf16* hh = b2 < 1024 ? Wq_h : Wk_h;
        bf16* ll = b2 < 1024 ? Wq_l : Wk_l;
        long long i = (long long)(b2 & 1023) * 256 + threadIdx.x;
        float4 v = W[i];
        bf16 a0 = (bf16)v.x, a1 = (bf16)v.y, a2 = (bf16)v.z, a3 = (bf16)v.w;
        bf16x4 hv = {a0, a1, a2, a3};
        bf16x4 lv = {(bf16)(v.x - (float)a0), (bf16)(v.y - (float)a1),
                     (bf16)(v.z - (float)a2), (bf16)(v.w - (float)a3)};
        *(bf16x4*)(hh + 4 * i) = hv;
        *(bf16x4*)(ll + 4 * i) = lv;
    } else {
        const int b3 = b - 10240;
        __shared__ float t[32][33];
        const int bx = (b3 & 31) * 32, by = (b3 >> 5) * 32;
        const int tx = threadIdx.x & 31, ty = threadIdx.x >> 5;
#pragma unroll
        for (int i = 0; i < 32; i += 8)
            t[ty + i][tx] = Wv[(long long)(by + ty + i) * 1024 + bx + tx];
        __syncthreads();
#pragma unroll
        for (int i = 0; i < 32; i += 8) {
            long long o = (long long)(bx + ty + i) * 1024 + by + tx;
            Wvt_f[o] = (f16)t[tx][ty + i];
        }
    }
}

// ---- D5: row softmax fp32 -> f16, vectorized ----
__global__ __launch_bounds__(256) void softmax_f16(const float* __restrict__ S,
                                                   f16* __restrict__ P, int n)
{
    const long long row = blockIdx.x;
    const float4* p = (const float4*)(S + row * (long long)n);
    f16* q = P + row * (long long)n;
    const int tid = threadIdx.x;
    const int wv = tid >> 6, lane = tid & 63;

    float4 va = p[tid], vb = p[tid + 256];
    float v[8] = {va.x, va.y, va.z, va.w, vb.x, vb.y, vb.z, vb.w};
    float m = -3.4e38f;
#pragma unroll
    for (int i = 0; i < 8; i++) m = fmaxf(m, v[i]);
#pragma unroll
    for (int off = 32; off > 0; off >>= 1) m = fmaxf(m, __shfl_xor(m, off, 64));

    __shared__ float red[4];
    if (lane == 0) red[wv] = m;
    __syncthreads();
    m = fmaxf(fmaxf(red[0], red[1]), fmaxf(red[2], red[3]));

    float s = 0.f;
#pragma unroll
    for (int i = 0; i < 8; i++) { v[i] = __expf(v[i] - m); s += v[i]; }
#pragma unroll
    for (int off = 32; off > 0; off >>= 1) s += __shfl_xor(s, off, 64);
    __syncthreads();
    if (lane == 0) red[wv] = s;
    __syncthreads();
    s = red[0] + red[1] + red[2] + red[3];

    const float inv = 1.0f / s;
    f16x4 o0 = {(f16)(v[0] * inv), (f16)(v[1] * inv), (f16)(v[2] * inv), (f16)(v[3] * inv)};
    f16x4 o1 = {(f16)(v[4] * inv), (f16)(v[5] * inv), (f16)(v[6] * inv), (f16)(v[7] * inv)};
    *(f16x4*)(q + tid * 4) = o0;
    *(f16x4*)(q + 1024 + tid * 4) = o1;
}

extern "C" void kernel_launch(void* const* d_in, const int* in_sizes, int n_in,
                              void* d_out, int out_size, void* d_ws, size_t ws_size,
                              hipStream_t stream) {
    const float* X  = (const float*)d_in[0];   // [8192,1024]
    const float* Wq = (const float*)d_in[1];   // [1024,1024]
    const float* Wk = (const float*)d_in[2];
    const float* Wv = (const float*)d_in[3];
    float* out = (float*)d_out;                // [8192,1024]

    char* w = (char*)d_ws;
    const long long MB = 1024LL * 1024;
    f16*  Xf    = (f16*) (w + 0 * MB);     // 16 MB
    bf16* Wq_h  = (bf16*)(w + 16 * MB);    // 2 MB
    bf16* Wq_l  = (bf16*)(w + 18 * MB);
    bf16* Wk_h  = (bf16*)(w + 20 * MB);
    bf16* Wk_l  = (bf16*)(w + 22 * MB);
    f16*  Wvt_f = (f16*) (w + 24 * MB);    // 2 MB (transposed)
    f16*  Mt_f  = (f16*) (w + 26 * MB);    // 2 MB
    f16*  T     = (f16*) (w + 28 * MB);    // 16 MB [8192,1024]
    f16*  Vt    = (f16*) (w + 44 * MB);    // 16 MB [4][1024][2048]
    float* Sc   = (float*)(w + 60 * MB);   // 64 MB
    f16*  P     = (f16*) (w + 124 * MB);   // 32 MB -> ends 156 MB

    dim3 blk(256);

    // D1: prep
    prep_all<<<dim3(11264), blk, 0, stream>>>(
        (const float4*)X, Xf, Wq, Wk, Wv, Wq_h, Wq_l, Wk_h, Wk_l, Wvt_f);

    // D2: Mt = Wk_s Wq_s^T (split bf16, 3-MFMA) -> f16
    gemm_bt<bf16, true, 1, 32><<<dim3(8, 8, 1), blk, 32768, stream>>>(
        Wk_h, Wk_l, Wq_h, Wq_l, nullptr, Mt_f,
        1024, 1024, 1024, 1024, 0, 0, 0);

    // D3: T || Vt  (256^2, 64KB LDS)
    tv8<<<dim3(8, 32), dim3(512), 65536, stream>>>(Xf, Mt_f, Wvt_f, T, Vt);

    // D4: Sc = T . Xf^T per batch -> fp32
    gemm8_k<0><<<dim3(8, 8, 4), dim3(512), 65536, stream>>>(
        T, Xf, Sc, nullptr, 1024, 1024, 1024, 2048,
        2048LL * 1024, 2048LL * 1024, 2048LL * 2048);

    // D5: softmax rows -> f16 P
    softmax_f16<<<dim3(4 * 2048), blk, 0, stream>>>(Sc, P, 2048);

    // D6: out = P . Vt^T
    gemm8_k<0><<<dim3(4, 8, 4), dim3(512), 65536, stream>>>(
        P, Vt, out, nullptr, 2048, 2048, 2048, 1024,
        2048LL * 2048, 1024LL * 2048, 2048LL * 1024);
}

// Round 5
// 273.305 us; speedup vs baseline: 1.1461x; 1.1461x over previous
//
#include <hip/hip_runtime.h>
#include <math.h>

// Round 13: fix R12's three measured defects, keep its verified schedule.
// 1) Pair-line LDS layout (128B lines = row pairs, 8-slot XOR swizzle) —
//    restores R2's measured-0-conflict geometry (R12's 64B rows = 3.1M conflicts).
// 2) XCD-aware tile swizzle (T1) on all 8-phase GEMMs for L2 panel reuse.
// 3) PV gets BM=128 variant (BMQ=1) -> grid 256 = full chip (was 128 = half idle).
//   D1 prep_all : X->f16 || Wq,Wk bf16-split || Wv transpose->f16
//   D2 mt       : Mt = Wk_s Wq_s^T (split-bf16 3-MFMA, 128^2) -> f16
//   D3 tv8      : T = Xf.Mt^T (bx<4) || Vt = (Xf.Wvt)^T (bx>=4)  [256^2]
//   D4 sc8      : Sc = T . Xf^T -> fp32                           [256^2]
//   D5 softmax  : P = softmax(Sc) -> f16
//   D6 pv8      : out = P . Vt^T                                  [128x256]

typedef __bf16 bf16;
typedef _Float16 f16;
typedef __bf16 bf16x8 __attribute__((ext_vector_type(8)));
typedef __bf16 bf16x4 __attribute__((ext_vector_type(4)));
typedef _Float16 f16x4 __attribute__((ext_vector_type(4)));
typedef _Float16 f16x8 __attribute__((ext_vector_type(8)));
typedef float  f32x4  __attribute__((ext_vector_type(4)));

template<typename E> struct vec8_of;
template<> struct vec8_of<bf16> { using type = bf16x8; };
template<> struct vec8_of<f16>  { using type = f16x8; };

__device__ inline f32x4 mfma16(bf16x8 a, bf16x8 b, f32x4 c) {
    return __builtin_amdgcn_mfma_f32_16x16x32_bf16(a, b, c, 0, 0, 0);
}
__device__ inline f32x4 mfma16(f16x8 a, f16x8 b, f32x4 c) {
    return __builtin_amdgcn_mfma_f32_16x16x32_f16(a, b, c, 0, 0, 0);
}

#define AS1 __attribute__((address_space(1)))
#define AS3 __attribute__((address_space(3)))

template<typename E>
__device__ inline void async_load16(const E* g, void* l) {
    __builtin_amdgcn_global_load_lds((const AS1 unsigned int*)g,
                                     (AS3 unsigned int*)l, 16, 0, 0);
}

#define SBAR()  do { __builtin_amdgcn_s_barrier(); __builtin_amdgcn_sched_barrier(0); } while (0)
#define WAITV(n) do { asm volatile("s_waitcnt vmcnt(" #n ")" ::: "memory"); __builtin_amdgcn_sched_barrier(0); } while (0)
#define WAITL() do { asm volatile("s_waitcnt lgkmcnt(0)" ::: "memory"); __builtin_amdgcn_sched_barrier(0); } while (0)

// XCD-aware bijective tile swizzle (nwg % 8 == 0): consecutive old-flat tiles
// (which share A/B panels) land on the same XCD's L2.
__device__ inline void xcd_swz(int nwg, int gx, int& bx, int& by) {
    const int flat = by * gx + bx;
    const int s = (flat & 7) * (nwg >> 3) + (flat >> 3);
    bx = s % gx;
    by = s / gx;
}

// ============== phase-split (BMQ*128)x256 f16 GEMM body, <=64KB LDS =========
// C[M,N] = sum_k A[m,k]*B[n,k]  (B in [N,K] layout). BM = BMQ*128, BN = 256.
// LDS chunk layout: pair-lines of 128B (rows 2l,2l+1), 8 slots, involution
// slot^=(line&7) applied on global-source AND read side; LDS dest linear.
// Per K=32 tile: p0 {read A+B0, stage B1(t+1), MFMA j0-1},
//                p1 {read B1, stage A/B0(t+2), MFMA j2-3}.
// Counted vmcnt: steady WAITV(BMQ+2); tails WAITV(1)/WAITV(0).
// OUT_MODE: 0 fp32; 1 f16; 2 f16 transposed per-batch (Vt path, BMQ=2 only).
template<int OUT_MODE, int BMQ>
__device__ __forceinline__ void gemm8_body(
    char* __restrict__ smraw,
    const f16* __restrict__ A, const f16* __restrict__ B,
    float* __restrict__ Cf, f16* __restrict__ Ch,
    int K, int lda, int ldb, int ldc,
    long long sA, long long sB, long long sC,
    int bx, int by, int bz)
{
    constexpr int B0OFF = BMQ * 8192;          // A chunk bytes
    constexpr int B1OFF = B0OFF + 8192;
    constexpr int BUFSZ = B0OFF + 16384;       // per-buffer bytes (A+B0+B1)

    A += (long long)bz * sA;
    B += (long long)bz * sB;

    const int tid  = threadIdx.x;
    const int lane = tid & 63;
    const int wave = tid >> 6;      // 0..7
    const int quad = lane >> 4;
    const int l16  = lane & 15;
    const int wm   = wave >> 2;     // 0..1  (M half)
    const int wn   = wave & 3;      // 0..3  (N quarter, 64 cols)

    const long long rowA0 = (long long)by * (BMQ * 128);
    const long long colB0 = (long long)bx * 256;

    // ---- staging precompute (pair-line, source pre-swizzled, dest linear) --
    const int line0 = tid >> 3;                     // 0..63
    const int slog  = (tid & 7) ^ (line0 & 7);      // logical slot 0..7
    const int aRow0 = line0 * 2 + (slog >> 2);      // 0..127
    const int aCol0 = (slog & 3) * 8;               // f16 k-offset
    const int bRow  = ((aRow0 >> 5) << 6) + (aRow0 & 31);  // B0 col map (bit5=0)

    const f16* aSrc0 = A + (rowA0 + aRow0) * lda + aCol0;
    const f16* aSrc1 = A + (rowA0 + 128 + aRow0) * lda + aCol0;   // BMQ==2 only
    const f16* b0Src = B + (colB0 + bRow) * ldb + aCol0;
    const f16* b1Src = b0Src + 32LL * ldb;

    const int dA0 = tid * 16, dA1 = 8192 + tid * 16;

    const int nt = K >> 5;

    auto stageA = [&](int t) {
        char* buf = smraw + (t & 1) * BUFSZ;
        async_load16(aSrc0 + t * 32, buf + dA0);
        if (BMQ == 2) async_load16(aSrc1 + t * 32, buf + dA1);
    };
    auto stageB0 = [&](int t) {
        char* buf = smraw + (t & 1) * BUFSZ;
        async_load16(b0Src + t * 32, buf + B0OFF + dA0);
    };
    auto stageB1 = [&](int t) {
        char* buf = smraw + (t & 1) * BUFSZ;
        async_load16(b1Src + t * 32, buf + B1OFF + dA0);
    };

    // ---- LDS read offsets (same involution) ----
    // row r, kslot q: addr = (r>>1)*128 + (((r&1)*4+q) ^ ((r>>1)&7))*16
    const int h    = l16 >> 1;
    const int lofs = h * 128 + ((((l16 & 1) * 4 + quad) ^ h) << 4);
    const int aoff = wm * (BMQ * 4096) + lofs;      // + i*1024 (i*8 lines)
    const int boff = wn * 2048 + lofs;              // + j*1024 within half

    f32x4 acc[4 * BMQ][4];
#pragma unroll
    for (int i = 0; i < 4 * BMQ; i++)
#pragma unroll
        for (int j = 0; j < 4; j++) acc[i][j] = (f32x4){0.f, 0.f, 0.f, 0.f};

    // ---- prologue: 2*BMQ+3 loads; WAITV(BMQ+2) lands A(0),B0(0) ----
    stageA(0); stageB0(0); stageB1(0);
    stageA(1); stageB0(1);
    if constexpr (BMQ == 2) WAITV(4); else WAITV(3);
    SBAR();

    for (int t = 0; t < nt; t++) {
        const char* buf = smraw + (t & 1) * BUFSZ;
        f16x8 av[4 * BMQ], bv[2];

        // ======== p0: A + B0 reads, MFMA j0-1, stage B1(t+1) ========
#pragma unroll
        for (int i = 0; i < 4 * BMQ; i++) av[i] = *(const f16x8*)(buf + aoff + i * 1024);
#pragma unroll
        for (int j = 0; j < 2; j++) bv[j] = *(const f16x8*)(buf + B0OFF + boff + j * 1024);
        if (t + 1 < nt) stageB1(t + 1);
        SBAR();
        WAITL();
        __builtin_amdgcn_s_setprio(1);
#pragma unroll
        for (int i = 0; i < 4 * BMQ; i++) {
            acc[i][0] = mfma16(av[i], bv[0], acc[i][0]);
            acc[i][1] = mfma16(av[i], bv[1], acc[i][1]);
        }
        __builtin_amdgcn_s_setprio(0);
        if (t + 1 < nt) { if constexpr (BMQ == 2) WAITV(4); else WAITV(3); }
        else WAITV(0);                                     // B1(t) landed
        SBAR();

        // ======== p1: B1 reads, MFMA j2-3, stage A/B0(t+2) ========
#pragma unroll
        for (int j = 0; j < 2; j++) bv[j] = *(const f16x8*)(buf + B1OFF + boff + j * 1024);
        if (t + 2 < nt) { stageA(t + 2); stageB0(t + 2); }
        SBAR();
        WAITL();
        __builtin_amdgcn_s_setprio(1);
#pragma unroll
        for (int i = 0; i < 4 * BMQ; i++) {
            acc[i][2] = mfma16(av[i], bv[0], acc[i][2]);
            acc[i][3] = mfma16(av[i], bv[1], acc[i][3]);
        }
        __builtin_amdgcn_s_setprio(0);
        if (t + 2 < nt) { if constexpr (BMQ == 2) WAITV(4); else WAITV(3); }
        else if (t + 1 < nt) WAITV(1);                     // A,B0(t+1) landed
        SBAR();
    }

    // ================= epilogue =================
    if constexpr (OUT_MODE == 2) {
        // Vt transpose via LDS [256 cols][72] f16 (36KB), 4 passes (h2, iq).
        auto tr = (f16(*)[72])smraw;
        const int batch = (int)(rowA0 >> 11);
        const long long rib = rowA0 & 2047;
        const int c  = tid >> 1;          // 0..255: Vt row (= C col)
        const int r0 = (tid & 1) << 5;    // 0 / 32
#pragma unroll
        for (int h2 = 0; h2 < 2; h2++)
#pragma unroll
            for (int iq = 0; iq < 2; iq++) {
                __syncthreads();
                if (wm == h2) {
#pragma unroll
                    for (int i2 = 0; i2 < 4; i2++)
#pragma unroll
                        for (int j = 0; j < 4; j++)
#pragma unroll
                            for (int e = 0; e < 4; e++)
                                tr[wn * 64 + j * 16 + l16][i2 * 16 + quad * 4 + e] =
                                    (f16)acc[iq * 4 + i2][j][e];
                }
                __syncthreads();
                f16* vt = Ch + (long long)batch * 1024 * 2048 +
                          (long long)(colB0 + c) * ldc + rib + h2 * 128 + iq * 64 + r0;
#pragma unroll
                for (int u = 0; u < 32; u += 8)
                    *(f16x8*)(vt + u) = *(const f16x8*)&tr[c][r0 + u];
            }
        return;
    }

    const long long cOff = (long long)bz * sC +
                           (rowA0 + wm * (BMQ * 64) + quad * 4) * (long long)ldc +
                           colB0 + wn * 64 + l16;
#pragma unroll
    for (int i = 0; i < 4 * BMQ; i++)
#pragma unroll
        for (int e = 0; e < 4; e++) {
            const long long ro = cOff + (long long)(i * 16 + e) * ldc;
            if (OUT_MODE == 0) {
                float* rp = Cf + ro;
#pragma unroll
                for (int j = 0; j < 4; j++) rp[j * 16] = acc[i][j][e];
            } else {
                f16* rp = Ch + ro;
#pragma unroll
                for (int j = 0; j < 4; j++) rp[j * 16] = (f16)acc[i][j][e];
            }
        }
}

// ---- D3: T = Xf.Mt^T (bx<4) || Vt = (Xf.Wvt)^T (bx>=4) ----
__global__ __launch_bounds__(512, 2) void tv8(
    const f16* __restrict__ Xf, const f16* __restrict__ Mt_f,
    const f16* __restrict__ Wvt_f, f16* __restrict__ T, f16* __restrict__ Vt)
{
    extern __shared__ char smraw[];
    int bx = blockIdx.x, by = blockIdx.y;
    xcd_swz(256, 8, bx, by);
    if (bx < 4)
        gemm8_body<1, 2>(smraw, Xf, Mt_f, nullptr, T, 1024, 1024, 1024, 1024,
                         0, 0, 0, bx, by, 0);
    else
        gemm8_body<2, 2>(smraw, Xf, Wvt_f, nullptr, Vt, 1024, 1024, 1024, 2048,
                         0, 0, 0, bx - 4, by, 0);
}

// ---- generic phase-split wrapper (D4 Sc, D6 PV) ----
template<int OUT_MODE, int BMQ>
__global__ __launch_bounds__(512, 2) void gemm8_k(
    const f16* __restrict__ A, const f16* __restrict__ B,
    float* __restrict__ Cf, f16* __restrict__ Ch,
    int K, int lda, int ldb, int ldc,
    long long sA, long long sB, long long sC)
{
    extern __shared__ char smraw[];
    int bx = blockIdx.x, by = blockIdx.y;
    xcd_swz(gridDim.x * gridDim.y, gridDim.x, bx, by);
    gemm8_body<OUT_MODE, BMQ>(smraw, A, B, Cf, Ch, K, lda, ldb, ldc, sA, sB, sC,
                              bx, by, blockIdx.z);
}

// ============== 128^2 kernel (Mt only: split-bf16 3-MFMA) — verified ========
template<typename E, bool SPLIT, int OUT_MODE, int BK>
__device__ __forceinline__ void gemm_body(
    char* __restrict__ smraw,
    const E* __restrict__ Ahi, const E* __restrict__ Alo,
    const E* __restrict__ Bhi, const E* __restrict__ Blo,
    float* __restrict__ Cf, f16* __restrict__ Ch,
    int K, int lda, int ldb, int ldc,
    long long sA, long long sB, long long sC,
    int bx, int by, int bz)
{
    using vec8 = typename vec8_of<E>::type;
    constexpr int TILE_BYTES = 128 * BK * (int)sizeof(E);
    constexpr int CPW = (TILE_BYTES / 1024) / 4;
    constexpr int SPR = (BK * (int)sizeof(E)) / 16;

    Ahi += (long long)bz * sA;
    Bhi += (long long)bz * sB;
    if (SPLIT) { Alo += (long long)bz * sA; Blo += (long long)bz * sB; }

    const int tid  = threadIdx.x;
    const int lane = tid & 63;
    const int wave = tid >> 6;
    const int quad = lane >> 4;
    const int l16  = lane & 15;
    const int wm   = (wave >> 1) * 64;
    const int wn   = (wave & 1) * 64;

    const long long rowA0 = (long long)by * 128;
    const long long colB0 = (long long)bx * 128;

    auto swz = [](int r) -> int { return (SPR == 8) ? (r & 7) : ((r >> 1) & 3); };

    int ofs[CPW], rr[CPW], cc8[CPW];
#pragma unroll
    for (int u = 0; u < CPW; u++) {
        ofs[u] = (wave * CPW + u) * 1024 + lane * 16;
        const int s = ofs[u] >> 4;
        rr[u]  = s / SPR;
        cc8[u] = (s & (SPR - 1)) ^ swz(rr[u]);
    }

    f32x4 acc[4][4];
#pragma unroll
    for (int i = 0; i < 4; i++)
#pragma unroll
        for (int j = 0; j < 4; j++) acc[i][j] = (f32x4){0.f, 0.f, 0.f, 0.f};

    for (int k0 = 0; k0 < K; k0 += BK) {
#pragma unroll
        for (int u = 0; u < CPW; u++) {
            async_load16(Ahi + (rowA0 + rr[u]) * lda + k0 + cc8[u] * 8, smraw + 0 * TILE_BYTES + ofs[u]);
            async_load16(Bhi + (colB0 + rr[u]) * ldb + k0 + cc8[u] * 8, smraw + 1 * TILE_BYTES + ofs[u]);
            if (SPLIT) {
                async_load16(Alo + (rowA0 + rr[u]) * lda + k0 + cc8[u] * 8, smraw + 2 * TILE_BYTES + ofs[u]);
                async_load16(Blo + (colB0 + rr[u]) * ldb + k0 + cc8[u] * 8, smraw + 3 * TILE_BYTES + ofs[u]);
            }
        }
        __syncthreads();

#pragma unroll
        for (int kh = 0; kh < BK / 32; kh++) {
            const int kc8 = kh * 4 + quad;
            vec8 a_hi[4], b_hi[4], a_lo[4], b_lo[4];
#pragma unroll
            for (int i = 0; i < 4; i++) {
                const int ra = wm + i * 16 + l16;
                const int rb = wn + i * 16 + l16;
                const int oa = ra * (SPR * 16) + ((kc8 ^ swz(ra)) << 4);
                const int ob = rb * (SPR * 16) + ((kc8 ^ swz(rb)) << 4);
                a_hi[i] = *(const vec8*)(smraw + 0 * TILE_BYTES + oa);
                b_hi[i] = *(const vec8*)(smraw + 1 * TILE_BYTES + ob);
                if (SPLIT) {
                    a_lo[i] = *(const vec8*)(smraw + 2 * TILE_BYTES + oa);
                    b_lo[i] = *(const vec8*)(smraw + 3 * TILE_BYTES + ob);
                }
            }
#pragma unroll
            for (int i = 0; i < 4; i++)
#pragma unroll
                for (int j = 0; j < 4; j++) {
                    acc[i][j] = mfma16(a_hi[i], b_hi[j], acc[i][j]);
                    if (SPLIT) {
                        acc[i][j] = mfma16(a_hi[i], b_lo[j], acc[i][j]);
                        acc[i][j] = mfma16(a_lo[i], b_hi[j], acc[i][j]);
                    }
                }
        }
        __syncthreads();
    }

    const long long cOff = (long long)bz * sC +
                           (rowA0 + wm + quad * 4) * (long long)ldc + colB0 + wn + l16;
#pragma unroll
    for (int i = 0; i < 4; i++)
#pragma unroll
        for (int e = 0; e < 4; e++) {
            const long long ro = cOff + (i * 16 + e) * ldc;
            if (OUT_MODE == 0) {
                float* rp = Cf + ro;
#pragma unroll
                for (int j = 0; j < 4; j++) rp[j * 16] = acc[i][j][e];
            } else {
                f16* rp = Ch + ro;
#pragma unroll
                for (int j = 0; j < 4; j++) rp[j * 16] = (f16)acc[i][j][e];
            }
        }
}

template<typename E, bool SPLIT, int OUT_MODE, int BK>
__global__ __launch_bounds__(256) void gemm_bt(
    const E* __restrict__ Ahi, const E* __restrict__ Alo,
    const E* __restrict__ Bhi, const E* __restrict__ Blo,
    float* __restrict__ Cf, f16* __restrict__ Ch,
    int K, int lda, int ldb, int ldc,
    long long sA, long long sB, long long sC)
{
    extern __shared__ char smraw[];
    gemm_body<E, SPLIT, OUT_MODE, BK>(smraw, Ahi, Alo, Bhi, Blo, Cf, Ch,
                                      K, lda, ldb, ldc, sA, sB, sC,
                                      blockIdx.x, blockIdx.y, blockIdx.z);
}

// ---- D1: X->f16 || Wq,Wk bf16-split || Wv transpose->f16 ----
__global__ __launch_bounds__(256) void prep_all(
    const float4* __restrict__ X, f16* __restrict__ Xf,
    const float* __restrict__ Wq, const float* __restrict__ Wk, const float* __restrict__ Wv,
    bf16* __restrict__ Wq_h, bf16* __restrict__ Wq_l,
    bf16* __restrict__ Wk_h, bf16* __restrict__ Wk_l,
    f16* __restrict__ Wvt_f)
{
    int b = blockIdx.x;
    if (b < 8192) {
        long long i = (long long)b * 256 + threadIdx.x;
        float4 v = X[i];
        f16x4 fv = {(f16)v.x, (f16)v.y, (f16)v.z, (f16)v.w};
        *(f16x4*)(Xf + 4 * i) = fv;
    } else if (b < 10240) {
        const int b2 = b - 8192;
        const float4* W = (const float4*)(b2 < 1024 ? Wq : Wk);
        bf16* hh = b2 < 1024 ? Wq_h : Wk_h;
        bf16* ll = b2 < 1024 ? Wq_l : Wk_l;
        long long i = (long long)(b2 & 1023) * 256 + threadIdx.x;
        float4 v = W[i];
        bf16 a0 = (bf16)v.x, a1 = (bf16)v.y, a2 = (bf16)v.z, a3 = (bf16)v.w;
        bf16x4 hv = {a0, a1, a2, a3};
        bf16x4 lv = {(bf16)(v.x - (float)a0), (bf16)(v.y - (float)a1),
                     (bf16)(v.z - (float)a2), (bf16)(v.w - (float)a3)};
        *(bf16x4*)(hh + 4 * i) = hv;
        *(bf16x4*)(ll + 4 * i) = lv;
    } else {
        const int b3 = b - 10240;
        __shared__ float t[32][33];
        const int bx = (b3 & 31) * 32, by = (b3 >> 5) * 32;
        const int tx = threadIdx.x & 31, ty = threadIdx.x >> 5;
#pragma unroll
        for (int i = 0; i < 32; i += 8)
            t[ty + i][tx] = Wv[(long long)(by + ty + i) * 1024 + bx + tx];
        __syncthreads();
#pragma unroll
        for (int i = 0; i < 32; i += 8) {
            long long o = (long long)(bx + ty + i) * 1024 + by + tx;
            Wvt_f[o] = (f16)t[tx][ty + i];
        }
    }
}

// ---- D5: row softmax fp32 -> f16, vectorized ----
__global__ __launch_bounds__(256) void softmax_f16(const float* __restrict__ S,
                                                   f16* __restrict__ P, int n)
{
    const long long row = blockIdx.x;
    const float4* p = (const float4*)(S + row * (long long)n);
    f16* q = P + row * (long long)n;
    const int tid = threadIdx.x;
    const int wv = tid >> 6, lane = tid & 63;

    float4 va = p[tid], vb = p[tid + 256];
    float v[8] = {va.x, va.y, va.z, va.w, vb.x, vb.y, vb.z, vb.w};
    float m = -3.4e38f;
#pragma unroll
    for (int i = 0; i < 8; i++) m = fmaxf(m, v[i]);
#pragma unroll
    for (int off = 32; off > 0; off >>= 1) m = fmaxf(m, __shfl_xor(m, off, 64));

    __shared__ float red[4];
    if (lane == 0) red[wv] = m;
    __syncthreads();
    m = fmaxf(fmaxf(red[0], red[1]), fmaxf(red[2], red[3]));

    float s = 0.f;
#pragma unroll
    for (int i = 0; i < 8; i++) { v[i] = __expf(v[i] - m); s += v[i]; }
#pragma unroll
    for (int off = 32; off > 0; off >>= 1) s += __shfl_xor(s, off, 64);
    __syncthreads();
    if (lane == 0) red[wv] = s;
    __syncthreads();
    s = red[0] + red[1] + red[2] + red[3];

    const float inv = 1.0f / s;
    f16x4 o0 = {(f16)(v[0] * inv), (f16)(v[1] * inv), (f16)(v[2] * inv), (f16)(v[3] * inv)};
    f16x4 o1 = {(f16)(v[4] * inv), (f16)(v[5] * inv), (f16)(v[6] * inv), (f16)(v[7] * inv)};
    *(f16x4*)(q + tid * 4) = o0;
    *(f16x4*)(q + 1024 + tid * 4) = o1;
}

extern "C" void kernel_launch(void* const* d_in, const int* in_sizes, int n_in,
                              void* d_out, int out_size, void* d_ws, size_t ws_size,
                              hipStream_t stream) {
    const float* X  = (const float*)d_in[0];   // [8192,1024]
    const float* Wq = (const float*)d_in[1];   // [1024,1024]
    const float* Wk = (const float*)d_in[2];
    const float* Wv = (const float*)d_in[3];
    float* out = (float*)d_out;                // [8192,1024]

    char* w = (char*)d_ws;
    const long long MB = 1024LL * 1024;
    f16*  Xf    = (f16*) (w + 0 * MB);     // 16 MB
    bf16* Wq_h  = (bf16*)(w + 16 * MB);    // 2 MB
    bf16* Wq_l  = (bf16*)(w + 18 * MB);
    bf16* Wk_h  = (bf16*)(w + 20 * MB);
    bf16* Wk_l  = (bf16*)(w + 22 * MB);
    f16*  Wvt_f = (f16*) (w + 24 * MB);    // 2 MB (transposed)
    f16*  Mt_f  = (f16*) (w + 26 * MB);    // 2 MB
    f16*  T     = (f16*) (w + 28 * MB);    // 16 MB [8192,1024]
    f16*  Vt    = (f16*) (w + 44 * MB);    // 16 MB [4][1024][2048]
    float* Sc   = (float*)(w + 60 * MB);   // 64 MB
    f16*  P     = (f16*) (w + 124 * MB);   // 32 MB -> ends 156 MB

    dim3 blk(256);

    // D1: prep
    prep_all<<<dim3(11264), blk, 0, stream>>>(
        (const float4*)X, Xf, Wq, Wk, Wv, Wq_h, Wq_l, Wk_h, Wk_l, Wvt_f);

    // D2: Mt = Wk_s Wq_s^T (split bf16, 3-MFMA) -> f16
    gemm_bt<bf16, true, 1, 32><<<dim3(8, 8, 1), blk, 32768, stream>>>(
        Wk_h, Wk_l, Wq_h, Wq_l, nullptr, Mt_f,
        1024, 1024, 1024, 1024, 0, 0, 0);

    // D3: T || Vt  (256^2, 64KB LDS, XCD-swizzled)
    tv8<<<dim3(8, 32), dim3(512), 65536, stream>>>(Xf, Mt_f, Wvt_f, T, Vt);

    // D4: Sc = T . Xf^T per batch -> fp32
    gemm8_k<0, 2><<<dim3(8, 8, 4), dim3(512), 65536, stream>>>(
        T, Xf, Sc, nullptr, 1024, 1024, 1024, 2048,
        2048LL * 1024, 2048LL * 1024, 2048LL * 2048);

    // D5: softmax rows -> f16 P
    softmax_f16<<<dim3(4 * 2048), blk, 0, stream>>>(Sc, P, 2048);

    // D6: out = P . Vt^T  (BM=128 -> grid 256 = full chip)
    gemm8_k<0, 1><<<dim3(4, 16, 4), dim3(512), 49152, stream>>>(
        P, Vt, out, nullptr, 2048, 2048, 2048, 1024,
        2048LL * 2048, 1024LL * 2048, 2048LL * 1024);
}